// Round 9
// baseline (201.274 us; speedup 1.0000x reference)
//
#include <hip/hip_runtime.h>

// Fused 3D local-NCC loss. Shapes (2,1,160,192,160) fp32,
// flat = ((n*D + d)*H + h)*W + w. 9x9x9 box window, zero-padded.
//
// v9: v8 structure (32x16x19 tile, 1080 blocks, 27=3x9 planes, 2 lgkm-only
// barriers/plane) with stage A2 rebuilt in ds_*_b128: 80 threads
// (5ch x 8 w-quads x 2 h-halves), float4 sliding 9-tap H-sum,
// 19 b128 reads + 8 b128 writes (g0..g3 cached, rows 4..6 re-read to hold
// VGPR ~60 => 4 blocks/CU). LDS cycles/block-plane ~1132 -> ~820.

namespace {
constexpr int Wd = 160, Hd = 192, Dd = 160, NB = 2;
constexpr long DSTRIDE = (long)Hd * Wd;        // 30720
constexpr long VOLUME  = (long)Dd * DSTRIDE;   // 4,915,200
constexpr int BW = 32, BH = 16, BD = 19;
constexpr int EH = BH + 8;                     // 24 halo rows
constexpr int NWB = 5, NHB = 12, NDB = 9;      // 9*19=171 covers 160
constexpr int NBLK = NB * NDB * NHB * NWB;     // 1080
constexpr int NT = 512;
constexpr int CH  = EH * BW;                   // 768 floats / channel (ws)
constexpr int HWC = BH * BW;                   // 512 floats / channel (hw)
constexpr int NPLANES = BD + 8;                // 27 = 3 * 9
constexpr float INV_WV = 1.0f / 729.0f;
constexpr float NEG_INV_TOTAL = -1.0f / 9830400.0f;
}

__device__ __forceinline__ void bar_lds() {
    asm volatile("s_waitcnt lgkmcnt(0)\n\ts_barrier" ::: "memory");
}

__device__ __forceinline__ float4 slide9(float v0, float v1, float v2, float v3,
                                         float v4, float v5, float v6, float v7,
                                         float v8, float v9, float v10, float v11) {
    float s8 = ((v0 + v1) + (v2 + v3)) + ((v4 + v5) + (v6 + v7)) + v8;
    float4 o;
    o.x = s8;
    o.y = o.x + (v9 - v0);
    o.z = o.y + (v10 - v1);
    o.w = o.z + (v11 - v2);
    return o;
}

#define ADD4(S, R) { (S).x += (R).x; (S).y += (R).y; (S).z += (R).z; (S).w += (R).w; }
#define SUB4(S, R) { (S).x -= (R).x; (S).y -= (R).y; (S).z -= (R).z; (S).w -= (R).w; }

__global__ __launch_bounds__(NT) void k_ncc(const float* __restrict__ I,
                                            const float* __restrict__ J,
                                            float* __restrict__ out) {
    __shared__ float ws[5 * CH];    // 15,360 B
    __shared__ float hw[5 * HWC];   // 10,240 B
    __shared__ float red[NT];       //  2,048 B

    const int tid = threadIdx.x;
    int bx = blockIdx.x;
    const int wb = bx % NWB; bx /= NWB;
    const int hb = bx % NHB; bx /= NHB;
    const int db = bx % NDB; bx /= NDB;
    const int n  = bx;
    const int w0 = wb * BW, h0 = hb * BH, d0 = db * BD;
    const long nvol = (long)n * VOLUME;

    // ---- Phase-A mapping (tid < 192): 24 rows x 8 four-wide segments ----
    const int seg = tid & 7;
    const int yy  = tid >> 3;
    const bool aJob = (tid < 192);
    const int ah    = h0 - 4 + yy;
    const int wbase = w0 - 4 + (seg << 2);
    const bool ahOk = aJob && ((unsigned)ah < (unsigned)Hd);
    const bool qok0 = ((unsigned)(wbase + 0) < (unsigned)Wd);
    const bool qok1 = ((unsigned)(wbase + 4) < (unsigned)Wd);
    const bool qok2 = ((unsigned)(wbase + 8) < (unsigned)Wd);
    const long roff = nvol + (long)ah * Wd + wbase + (long)(d0 - 4) * DSTRIDE;
    const float* aI = I + roff;
    const float* aJ = J + roff;

    // ---- Phase-A2 mapping (tid < 80): 5ch x 2 h-halves x 8 w-quads ------
    const int c2 = tid >> 4;                 // 0..4
    const int hq = (tid >> 3) & 1;           // 0..1
    const int qq = tid & 7;                  // 0..7
    const float4* const a2src =
        (const float4*)(ws + c2 * CH) + (hq * 8) * (BW / 4) + qq;
    float4* const a2dst =
        (float4*)(hw + c2 * HWC) + (hq * 8) * (BW / 4) + qq;

    // ---- Phase-B mapping ----
    const int tx = tid & 31, ty = tid >> 5;

    // Prefetch registers (explicit scalars -> never spilled).
    float4 pI0, pI1, pI2, pJ0, pJ1, pJ2;

#define ISSUE(PP)                                                            \
    do {                                                                     \
        const bool _pv = ahOk && ((unsigned)(PP) < (unsigned)Dd);            \
        pI0 = (_pv && qok0) ? *(const float4*)(aI + 0) : float4{0, 0, 0, 0}; \
        pI1 = (_pv && qok1) ? *(const float4*)(aI + 4) : float4{0, 0, 0, 0}; \
        pI2 = (_pv && qok2) ? *(const float4*)(aI + 8) : float4{0, 0, 0, 0}; \
        pJ0 = (_pv && qok0) ? *(const float4*)(aJ + 0) : float4{0, 0, 0, 0}; \
        pJ1 = (_pv && qok1) ? *(const float4*)(aJ + 4) : float4{0, 0, 0, 0}; \
        pJ2 = (_pv && qok2) ? *(const float4*)(aJ + 8) : float4{0, 0, 0, 0}; \
    } while (0)

    float hist[9][5];
#pragma unroll
    for (int k = 0; k < 9; ++k)
#pragma unroll
        for (int c = 0; c < 5; ++c) hist[k][c] = 0.0f;
    float sa[5] = {0, 0, 0, 0, 0};
    float acc = 0.0f;

    ISSUE(d0 - 4);   // prime

#pragma unroll 1
    for (int M = 0; M < 3; ++M) {
#pragma unroll
        for (int u = 0; u < 9; ++u) {
            const int t = 9 * M + u;
            const int p = d0 - 4 + t;
            const bool pvalid = ((unsigned)p < (unsigned)Dd);

            // ---------- Phase A: consume prefetch -> W-slide -> LDS ------
            if (pvalid && aJob) {
                const float a0 = pI0.x, a1 = pI0.y, a2 = pI0.z, a3 = pI0.w;
                const float a4 = pI1.x, a5 = pI1.y, a6 = pI1.z, a7 = pI1.w;
                const float a8 = pI2.x, a9 = pI2.y, a10 = pI2.z, a11 = pI2.w;
                const float b0 = pJ0.x, b1 = pJ0.y, b2 = pJ0.z, b3 = pJ0.w;
                const float b4 = pJ1.x, b5 = pJ1.y, b6 = pJ1.z, b7 = pJ1.w;
                const float b8 = pJ2.x, b9 = pJ2.y, b10 = pJ2.z, b11 = pJ2.w;
                float* const wab = ws + yy * BW + (seg << 2);
                *(float4*)(wab + 0 * CH) =
                    slide9(a0, a1, a2, a3, a4, a5, a6, a7, a8, a9, a10, a11);
                *(float4*)(wab + 1 * CH) =
                    slide9(b0, b1, b2, b3, b4, b5, b6, b7, b8, b9, b10, b11);
                *(float4*)(wab + 2 * CH) =
                    slide9(a0 * a0, a1 * a1, a2 * a2, a3 * a3, a4 * a4, a5 * a5,
                           a6 * a6, a7 * a7, a8 * a8, a9 * a9, a10 * a10, a11 * a11);
                *(float4*)(wab + 3 * CH) =
                    slide9(b0 * b0, b1 * b1, b2 * b2, b3 * b3, b4 * b4, b5 * b5,
                           b6 * b6, b7 * b7, b8 * b8, b9 * b9, b10 * b10, b11 * b11);
                *(float4*)(wab + 4 * CH) =
                    slide9(a0 * b0, a1 * b1, a2 * b2, a3 * b3, a4 * b4, a5 * b5,
                           a6 * b6, a7 * b7, a8 * b8, a9 * b9, a10 * b10, a11 * b11);
            }
            // Issue next plane's loads (in flight across both barriers).
            aI += DSTRIDE; aJ += DSTRIDE;
            if (t < NPLANES - 1) { ISSUE(p + 1); }

            bar_lds();

            // ---------- Phase A2: float4 sliding 9-tap H-sum -> hw -------
            if (pvalid && tid < 80) {
                const float4* const src = a2src;
                float4* const dst = a2dst;
                float4 g0 = src[0 * 8], g1 = src[1 * 8];
                float4 g2 = src[2 * 8], g3 = src[3 * 8];
                float4 t4 = src[4 * 8], t5 = src[5 * 8];
                float4 t6 = src[6 * 8], t7 = src[7 * 8];
                float4 s;
                s.x = ((g0.x + g1.x) + (g2.x + g3.x)) + ((t4.x + t5.x) + (t6.x + t7.x));
                s.y = ((g0.y + g1.y) + (g2.y + g3.y)) + ((t4.y + t5.y) + (t6.y + t7.y));
                s.z = ((g0.z + g1.z) + (g2.z + g3.z)) + ((t4.z + t5.z) + (t6.z + t7.z));
                s.w = ((g0.w + g1.w) + (g2.w + g3.w)) + ((t4.w + t5.w) + (t6.w + t7.w));
                float4 r;
                r = src[ 8 * 8]; ADD4(s, r); dst[0 * 8] = s; SUB4(s, g0);
                r = src[ 9 * 8]; ADD4(s, r); dst[1 * 8] = s; SUB4(s, g1);
                r = src[10 * 8]; ADD4(s, r); dst[2 * 8] = s; SUB4(s, g2);
                r = src[11 * 8]; ADD4(s, r); dst[3 * 8] = s; SUB4(s, g3);
                r = src[12 * 8]; ADD4(s, r); dst[4 * 8] = s;
                g0 = src[4 * 8]; SUB4(s, g0);
                r = src[13 * 8]; ADD4(s, r); dst[5 * 8] = s;
                g1 = src[5 * 8]; SUB4(s, g1);
                r = src[14 * 8]; ADD4(s, r); dst[6 * 8] = s;
                g2 = src[6 * 8]; SUB4(s, g2);
                r = src[15 * 8]; ADD4(s, r); dst[7 * 8] = s;
            }

            bar_lds();

            // ---------- Phase B: 5 reads + D-window + cc -----------------
            float h5[5];
            if (pvalid) {
#pragma unroll
                for (int c = 0; c < 5; ++c)
                    h5[c] = hw[c * HWC + ty * BW + tx];
            } else {
#pragma unroll
                for (int c = 0; c < 5; ++c) h5[c] = 0.0f;
            }
#pragma unroll
            for (int c = 0; c < 5; ++c) sa[c] += h5[c];
            const int dout = d0 + t - 8;
            if (t >= 8 && dout < Dd) {
                const float cross = sa[4] - sa[0] * sa[1] * INV_WV;
                const float iv    = sa[2] - sa[0] * sa[0] * INV_WV;
                const float jv    = sa[3] - sa[1] * sa[1] * INV_WV;
                acc += (cross * cross) * __builtin_amdgcn_rcpf(iv * jv + 1e-5f);
            }
#pragma unroll
            for (int c = 0; c < 5; ++c) sa[c] -= hist[(u + 1) % 9][c];
#pragma unroll
            for (int c = 0; c < 5; ++c) hist[u][c] = h5[c];
        }
    }
#undef ISSUE

    // ---- block reduction + global atomic (pre-scaled) ----
    red[tid] = acc;
    __syncthreads();
    for (int off = NT / 2; off > 0; off >>= 1) {
        if (tid < off) red[tid] += red[tid + off];
        __syncthreads();
    }
    if (tid == 0) atomicAdd(out, red[0] * NEG_INV_TOTAL);
}

extern "C" void kernel_launch(void* const* d_in, const int* in_sizes, int n_in,
                              void* d_out, int out_size, void* d_ws, size_t ws_size,
                              hipStream_t stream) {
    const float* I = (const float*)d_in[0];
    const float* J = (const float*)d_in[1];
    float* out = (float*)d_out;

    hipMemsetAsync(d_out, 0, sizeof(float), stream);   // stream-ordered, graph-safe
    k_ncc<<<NBLK, NT, 0, stream>>>(I, J, out);
}

// Round 10
// 184.902 us; speedup vs baseline: 1.0885x; 1.0885x over previous
//
#include <hip/hip_runtime.h>

// Fused 3D local-NCC loss. Shapes (2,1,160,192,160) fp32,
// flat = ((n*D + d)*H + h)*W + w. 9x9x9 box window, zero-padded.
//
// v10: v8 dataflow (2 lgkm-only barriers/plane; b128 LDS *writes* ok,
// b64 LDS reads ok, b128 LDS reads FORBIDDEN -- v9 measured 1.7M conflicts).
// Geometry rebalanced for residency: 32(w) x 12(h) x 19(d) tile, NT=384,
// 1440 blocks (5.6/CU), LDS 22 KB, 6 waves/block -> ~4 blocks/CU resident.
// A2 minimal-read: 80 float2-threads, each ws row read exactly once
// (20 b64 reads + 12 b64 writes; r8..r10 cached for late subtracts).

namespace {
constexpr int Wd = 160, Hd = 192, Dd = 160, NB = 2;
constexpr long DSTRIDE = (long)Hd * Wd;        // 30720
constexpr long VOLUME  = (long)Dd * DSTRIDE;   // 4,915,200
constexpr int BW = 32, BH = 12, BD = 19;
constexpr int EH = BH + 8;                     // 20 halo rows
constexpr int NWB = 5, NHB = 16, NDB = 9;      // 9*19=171 covers 160
constexpr int NBLK = NB * NDB * NHB * NWB;     // 1440
constexpr int NT = 384;                        // 6 waves
constexpr int CH  = EH * BW;                   // 640 floats / channel (ws)
constexpr int HWC = BH * BW;                   // 384 floats / channel (hw)
constexpr int NPLANES = BD + 8;                // 27 = 3 * 9
constexpr float INV_WV = 1.0f / 729.0f;
constexpr float NEG_INV_TOTAL = -1.0f / 9830400.0f;
}

__device__ __forceinline__ void bar_lds() {
    asm volatile("s_waitcnt lgkmcnt(0)\n\ts_barrier" ::: "memory");
}

__device__ __forceinline__ float4 slide9(float v0, float v1, float v2, float v3,
                                         float v4, float v5, float v6, float v7,
                                         float v8, float v9, float v10, float v11) {
    float s8 = ((v0 + v1) + (v2 + v3)) + ((v4 + v5) + (v6 + v7)) + v8;
    float4 o;
    o.x = s8;
    o.y = o.x + (v9 - v0);
    o.z = o.y + (v10 - v1);
    o.w = o.z + (v11 - v2);
    return o;
}

__global__ __launch_bounds__(NT) void k_ncc(const float* __restrict__ I,
                                            const float* __restrict__ J,
                                            float* __restrict__ out) {
    __shared__ float ws[5 * CH];    // 12,800 B
    __shared__ float hw[5 * HWC];   //  7,680 B
    __shared__ float red[NT];       //  1,536 B

    const int tid = threadIdx.x;
    int bx = blockIdx.x;
    const int wb = bx % NWB; bx /= NWB;
    const int hb = bx % NHB; bx /= NHB;
    const int db = bx % NDB; bx /= NDB;
    const int n  = bx;
    const int w0 = wb * BW, h0 = hb * BH, d0 = db * BD;
    const long nvol = (long)n * VOLUME;

    // ---- Phase-A mapping (tid < 160): 20 rows x 8 four-wide segments ----
    const int seg = tid & 7;
    const int yy  = tid >> 3;
    const bool aJob = (tid < 160);
    const int ah    = h0 - 4 + yy;
    const int wbase = w0 - 4 + (seg << 2);
    const bool ahOk = aJob && ((unsigned)ah < (unsigned)Hd);
    const bool qok0 = ((unsigned)(wbase + 0) < (unsigned)Wd);
    const bool qok1 = ((unsigned)(wbase + 4) < (unsigned)Wd);
    const bool qok2 = ((unsigned)(wbase + 8) < (unsigned)Wd);
    const long roff = nvol + (long)ah * Wd + wbase + (long)(d0 - 4) * DSTRIDE;
    const float* aI = I + roff;
    const float* aJ = J + roff;

    // ---- Phase-A2 mapping (tid < 80): 5 ch x 16 float2 lanes ------------
    const int c2 = tid >> 4;                 // 0..4
    const int wp = tid & 15;                 // 0..15
    const float2* const a2src = (const float2*)(ws + c2 * CH) + wp;
    float2* const a2dst = (float2*)(hw + c2 * HWC) + wp;

    // ---- Phase-B mapping ----
    const int tx = tid & 31, ty = tid >> 5;  // 32 x 12

    // Prefetch registers (explicit scalars -> never spilled).
    float4 pI0, pI1, pI2, pJ0, pJ1, pJ2;

#define ISSUE(PP)                                                            \
    do {                                                                     \
        const bool _pv = ahOk && ((unsigned)(PP) < (unsigned)Dd);            \
        pI0 = (_pv && qok0) ? *(const float4*)(aI + 0) : float4{0, 0, 0, 0}; \
        pI1 = (_pv && qok1) ? *(const float4*)(aI + 4) : float4{0, 0, 0, 0}; \
        pI2 = (_pv && qok2) ? *(const float4*)(aI + 8) : float4{0, 0, 0, 0}; \
        pJ0 = (_pv && qok0) ? *(const float4*)(aJ + 0) : float4{0, 0, 0, 0}; \
        pJ1 = (_pv && qok1) ? *(const float4*)(aJ + 4) : float4{0, 0, 0, 0}; \
        pJ2 = (_pv && qok2) ? *(const float4*)(aJ + 8) : float4{0, 0, 0, 0}; \
    } while (0)

    float hist[9][5];
#pragma unroll
    for (int k = 0; k < 9; ++k)
#pragma unroll
        for (int c = 0; c < 5; ++c) hist[k][c] = 0.0f;
    float sa[5] = {0, 0, 0, 0, 0};
    float acc = 0.0f;

    ISSUE(d0 - 4);   // prime

#pragma unroll 1
    for (int M = 0; M < 3; ++M) {
#pragma unroll
        for (int u = 0; u < 9; ++u) {
            const int t = 9 * M + u;
            const int p = d0 - 4 + t;
            const bool pvalid = ((unsigned)p < (unsigned)Dd);

            // ---------- Phase A: consume prefetch -> W-slide -> LDS ------
            if (pvalid && aJob) {
                const float a0 = pI0.x, a1 = pI0.y, a2 = pI0.z, a3 = pI0.w;
                const float a4 = pI1.x, a5 = pI1.y, a6 = pI1.z, a7 = pI1.w;
                const float a8 = pI2.x, a9 = pI2.y, a10 = pI2.z, a11 = pI2.w;
                const float b0 = pJ0.x, b1 = pJ0.y, b2 = pJ0.z, b3 = pJ0.w;
                const float b4 = pJ1.x, b5 = pJ1.y, b6 = pJ1.z, b7 = pJ1.w;
                const float b8 = pJ2.x, b9 = pJ2.y, b10 = pJ2.z, b11 = pJ2.w;
                float* const wab = ws + yy * BW + (seg << 2);
                *(float4*)(wab + 0 * CH) =
                    slide9(a0, a1, a2, a3, a4, a5, a6, a7, a8, a9, a10, a11);
                *(float4*)(wab + 1 * CH) =
                    slide9(b0, b1, b2, b3, b4, b5, b6, b7, b8, b9, b10, b11);
                *(float4*)(wab + 2 * CH) =
                    slide9(a0 * a0, a1 * a1, a2 * a2, a3 * a3, a4 * a4, a5 * a5,
                           a6 * a6, a7 * a7, a8 * a8, a9 * a9, a10 * a10, a11 * a11);
                *(float4*)(wab + 3 * CH) =
                    slide9(b0 * b0, b1 * b1, b2 * b2, b3 * b3, b4 * b4, b5 * b5,
                           b6 * b6, b7 * b7, b8 * b8, b9 * b9, b10 * b10, b11 * b11);
                *(float4*)(wab + 4 * CH) =
                    slide9(a0 * b0, a1 * b1, a2 * b2, a3 * b3, a4 * b4, a5 * b5,
                           a6 * b6, a7 * b7, a8 * b8, a9 * b9, a10 * b10, a11 * b11);
            }
            // Issue next plane's loads (in flight across both barriers).
            aI += DSTRIDE; aJ += DSTRIDE;
            if (t < NPLANES - 1) { ISSUE(p + 1); }

            bar_lds();

            // ---------- Phase A2: float2 sliding 9-tap H-sum -> hw -------
            // Each ws row read exactly once (20 reads), 12 writes.
            if (pvalid && tid < 80) {
                const float2* const src = a2src;
                float2* const dst = a2dst;
                float2 g0 = src[0 * 16], g1 = src[1 * 16];
                float2 g2 = src[2 * 16], g3 = src[3 * 16];
                float2 g4 = src[4 * 16], g5 = src[5 * 16];
                float2 g6 = src[6 * 16], g7 = src[7 * 16];
                float2 s;
                s.x = ((g0.x + g1.x) + (g2.x + g3.x)) + ((g4.x + g5.x) + (g6.x + g7.x));
                s.y = ((g0.y + g1.y) + (g2.y + g3.y)) + ((g4.y + g5.y) + (g6.y + g7.y));
                float2 r, h8, h9, h10;
                r = src[ 8 * 16]; h8 = r;
                s.x += r.x; s.y += r.y; dst[ 0 * 16] = s; s.x -= g0.x; s.y -= g0.y;
                r = src[ 9 * 16]; h9 = r;
                s.x += r.x; s.y += r.y; dst[ 1 * 16] = s; s.x -= g1.x; s.y -= g1.y;
                r = src[10 * 16]; h10 = r;
                s.x += r.x; s.y += r.y; dst[ 2 * 16] = s; s.x -= g2.x; s.y -= g2.y;
                r = src[11 * 16];
                s.x += r.x; s.y += r.y; dst[ 3 * 16] = s; s.x -= g3.x; s.y -= g3.y;
                r = src[12 * 16];
                s.x += r.x; s.y += r.y; dst[ 4 * 16] = s; s.x -= g4.x; s.y -= g4.y;
                r = src[13 * 16];
                s.x += r.x; s.y += r.y; dst[ 5 * 16] = s; s.x -= g5.x; s.y -= g5.y;
                r = src[14 * 16];
                s.x += r.x; s.y += r.y; dst[ 6 * 16] = s; s.x -= g6.x; s.y -= g6.y;
                r = src[15 * 16];
                s.x += r.x; s.y += r.y; dst[ 7 * 16] = s; s.x -= g7.x; s.y -= g7.y;
                r = src[16 * 16];
                s.x += r.x; s.y += r.y; dst[ 8 * 16] = s; s.x -= h8.x; s.y -= h8.y;
                r = src[17 * 16];
                s.x += r.x; s.y += r.y; dst[ 9 * 16] = s; s.x -= h9.x; s.y -= h9.y;
                r = src[18 * 16];
                s.x += r.x; s.y += r.y; dst[10 * 16] = s; s.x -= h10.x; s.y -= h10.y;
                r = src[19 * 16];
                s.x += r.x; s.y += r.y; dst[11 * 16] = s;
            }

            bar_lds();

            // ---------- Phase B: 5 reads + D-window + cc -----------------
            float h5[5];
            if (pvalid) {
#pragma unroll
                for (int c = 0; c < 5; ++c)
                    h5[c] = hw[c * HWC + ty * BW + tx];
            } else {
#pragma unroll
                for (int c = 0; c < 5; ++c) h5[c] = 0.0f;
            }
#pragma unroll
            for (int c = 0; c < 5; ++c) sa[c] += h5[c];
            const int dout = d0 + t - 8;
            if (t >= 8 && dout < Dd) {
                const float cross = sa[4] - sa[0] * sa[1] * INV_WV;
                const float iv    = sa[2] - sa[0] * sa[0] * INV_WV;
                const float jv    = sa[3] - sa[1] * sa[1] * INV_WV;
                acc += (cross * cross) * __builtin_amdgcn_rcpf(iv * jv + 1e-5f);
            }
#pragma unroll
            for (int c = 0; c < 5; ++c) sa[c] -= hist[(u + 1) % 9][c];
#pragma unroll
            for (int c = 0; c < 5; ++c) hist[u][c] = h5[c];
        }
    }
#undef ISSUE

    // ---- block reduction (384 = 256 + 128 pre-fold) + global atomic ----
    red[tid] = acc;
    __syncthreads();
    if (tid < 128) red[tid] += red[tid + 256];
    __syncthreads();
    for (int off = 128; off > 0; off >>= 1) {
        if (tid < off) red[tid] += red[tid + off];
        __syncthreads();
    }
    if (tid == 0) atomicAdd(out, red[0] * NEG_INV_TOTAL);
}

extern "C" void kernel_launch(void* const* d_in, const int* in_sizes, int n_in,
                              void* d_out, int out_size, void* d_ws, size_t ws_size,
                              hipStream_t stream) {
    const float* I = (const float*)d_in[0];
    const float* J = (const float*)d_in[1];
    float* out = (float*)d_out;

    hipMemsetAsync(d_out, 0, sizeof(float), stream);   // stream-ordered, graph-safe
    k_ncc<<<NBLK, NT, 0, stream>>>(I, J, out);
}